// Round 7
// baseline (81.419 us; speedup 1.0000x reference)
//
#include <hip/hip_runtime.h>
#include <math.h>

constexpr int B_ = 256;
constexpr int D_ = 128;
constexpr int N_ = 65536;
constexpr int P_ = 100;
constexpr int K_ = 4096;
constexpr int P2_ = 10;
constexpr int KP_ = K_ + P_;       // 4196
constexpr int OC_ = P2_ + K_;      // 4106
constexpr float T_ = 0.07f;

typedef __attribute__((ext_vector_type(8))) short bf16x8;
typedef __attribute__((ext_vector_type(4))) float f32x4v;

// ============================ FAST PATH =============================
// S[b][row] = v2[b] . mem1[row]  computed via split-bf16 MFMA (3 passes:
// hh + hl + lh; residual ~2^-14 per element -> out absmax ~2e-3 << 0.165).

// ---- kernel P: split v2 into bf16 hi/lo (truncation split, al exact) ----
__global__ __launch_bounds__(256) void k_prep(
    const float* __restrict__ v2, unsigned short* __restrict__ v2h,
    unsigned short* __restrict__ v2l)
{
  const int i4 = blockIdx.x * 256 + threadIdx.x;   // 8192 float4 total
  const float4 v = reinterpret_cast<const float4*>(v2)[i4];
  const float f[4] = {v.x, v.y, v.z, v.w};
  unsigned short h[4], l[4];
#pragma unroll
  for (int j = 0; j < 4; ++j) {
    const unsigned u = __float_as_uint(f[j]);
    h[j] = (unsigned short)(u >> 16);
    const float al = f[j] - __uint_as_float(u & 0xFFFF0000u);
    l[j] = (unsigned short)(__float_as_uint(al) >> 16);
  }
  ushort4 hv = {h[0], h[1], h[2], h[3]};
  ushort4 lv = {l[0], l[1], l[2], l[3]};
  reinterpret_cast<ushort4*>(v2h)[i4] = hv;
  reinterpret_cast<ushort4*>(v2l)[i4] = lv;
}

__device__ inline void split8(const f32x4v lo, const f32x4v hi,
                              bf16x8& h, bf16x8& l) {
#pragma unroll
  for (int j = 0; j < 4; ++j) {
    const unsigned u = __float_as_uint(lo[j]);
    h[j] = (short)(u >> 16);
    const float al = lo[j] - __uint_as_float(u & 0xFFFF0000u);
    l[j] = (short)(__float_as_uint(al) >> 16);
  }
#pragma unroll
  for (int j = 0; j < 4; ++j) {
    const unsigned u = __float_as_uint(hi[j]);
    h[4 + j] = (short)(u >> 16);
    const float al = hi[j] - __uint_as_float(u & 0xFFFF0000u);
    l[4 + j] = (short)(__float_as_uint(al) >> 16);
  }
}

// ---- kernel G: blocks [0,512) GEMM row-tiles of 128; [512,2560) copy ----
constexpr int GEMMB_ = 512;
__global__ __launch_bounds__(512) void k_gemm(
    const float* __restrict__ mem1, const unsigned short* __restrict__ v2h,
    const unsigned short* __restrict__ v2l, float* __restrict__ S,
    float* __restrict__ outmem)
{
  const int tid = threadIdx.x;
  if (blockIdx.x >= GEMMB_) {
    // copy memory_v1 -> outmem (16 KB per block)
    const int g = blockIdx.x - GEMMB_;
    const float4* __restrict__ s4 = reinterpret_cast<const float4*>(mem1) + (size_t)g * 1024;
    float4* __restrict__ d4 = reinterpret_cast<float4*>(outmem) + (size_t)g * 1024;
    d4[tid] = s4[tid];
    d4[tid + 512] = s4[tid + 512];
    return;
  }
  __shared__ float tile[16384];                    // 128 rows x 128 k fp32, swizzled
  const int r0 = blockIdx.x * 128;
  // stage: global linear read, XOR-swizzled LDS write (T2: break 512B stride)
  {
    const float4* __restrict__ gsrc = reinterpret_cast<const float4*>(mem1 + (size_t)r0 * D_);
    char* tb = (char*)tile;
#pragma unroll
    for (int q = 0; q < 8; ++q) {
      const int li = q * 512 + tid;                // float4 index
      const float4 v = gsrc[li];
      const int row = li >> 5;
      const int off = (li & 31) * 16;
      *reinterpret_cast<float4*>(tb + row * 512 + (off ^ ((row & 7) << 4))) = v;
    }
  }
  __syncthreads();
  const int wid = tid >> 6, lane = tid & 63;
  const int mb = (wid >> 1) * 64;                  // b-offset of wave tile
  const int nb = (wid & 1) * 64;                   // row-offset of wave tile
  const int klane8 = (lane >> 4) * 8;
  f32x4v acc[4][4];
#pragma unroll
  for (int m = 0; m < 4; ++m)
#pragma unroll
    for (int n = 0; n < 4; ++n) acc[m][n] = {0.f, 0.f, 0.f, 0.f};

  const char* tb = (const char*)tile;
#pragma unroll
  for (int kk = 0; kk < 4; ++kk) {
    const int ks = kk * 32;
    bf16x8 ah[4], al[4];
#pragma unroll
    for (int m = 0; m < 4; ++m) {
      const size_t o = (size_t)(mb + m * 16 + (lane & 15)) * D_ + ks + klane8;
      ah[m] = *reinterpret_cast<const bf16x8*>(v2h + o);
      al[m] = *reinterpret_cast<const bf16x8*>(v2l + o);
    }
#pragma unroll
    for (int n = 0; n < 4; ++n) {
      const int r_loc = nb + n * 16 + (lane & 15);
      const int sw = (r_loc & 7) << 4;
      const int kb = (ks + klane8) * 4;
      const char* rb = tb + r_loc * 512;
      const f32x4v p0 = *reinterpret_cast<const f32x4v*>(rb + ((kb) ^ sw));
      const f32x4v p1 = *reinterpret_cast<const f32x4v*>(rb + ((kb + 16) ^ sw));
      bf16x8 bh, bl;
      split8(p0, p1, bh, bl);
#pragma unroll
      for (int m = 0; m < 4; ++m) {
        acc[m][n] = __builtin_amdgcn_mfma_f32_16x16x32_bf16(ah[m], bh, acc[m][n], 0, 0, 0);
        acc[m][n] = __builtin_amdgcn_mfma_f32_16x16x32_bf16(ah[m], bl, acc[m][n], 0, 0, 0);
        acc[m][n] = __builtin_amdgcn_mfma_f32_16x16x32_bf16(al[m], bh, acc[m][n], 0, 0, 0);
      }
    }
  }
  // epilogue: D[m=(lane>>4)*4+reg][n=lane&15]  ->  S[b][row]
#pragma unroll
  for (int m = 0; m < 4; ++m) {
#pragma unroll
    for (int n = 0; n < 4; ++n) {
      const int row = r0 + nb + n * 16 + (lane & 15);
#pragma unroll
      for (int reg = 0; reg < 4; ++reg) {
        const int b = mb + m * 16 + (lane >> 4) * 4 + reg;
        S[(size_t)b * N_ + row] = acc[m][n][reg];
      }
    }
  }
}

// ---- kernel C: [0,512) neg exp gather; [512,768) cos+select; [768,1024) y-upd
__global__ __launch_bounds__(256) void k_score(
    const float* __restrict__ v1, const float* __restrict__ v2,
    const int* __restrict__ idx, const float* __restrict__ mem1,
    const float* __restrict__ mem2, const float* __restrict__ S,
    const int* __restrict__ y, float* __restrict__ out,
    float* __restrict__ outmem, double* __restrict__ wpart)
{
  const int tid = threadIdx.x;
  const unsigned bid = blockIdx.x;
  __shared__ double lacc[4];
  __shared__ float sbuf[2 * D_];
  __shared__ double sdiff[P_];
  __shared__ float swout[P_];
  __shared__ double dsn2[P_], dss[P_];
  __shared__ double dinv[2];

  if (bid < 512) {
    const int b = bid >> 1, half = bid & 1;
    const int* __restrict__ idxb = idx + (size_t)b * KP_ + P_ + half * 2048;
    float* __restrict__ outb = out + (size_t)b * OC_ + P2_ + half * 2048;
    const float* __restrict__ Sb = S + (size_t)b * N_;
    int rows[8];
#pragma unroll
    for (int i = 0; i < 8; ++i) rows[i] = idxb[i * 256 + tid];
    float sv[8];
#pragma unroll
    for (int i = 0; i < 8; ++i) sv[i] = Sb[rows[i]];
    double de = 0.0;
#pragma unroll
    for (int i = 0; i < 8; ++i) {
      const float e = expf(sv[i] * (1.0f / T_));
      outb[i * 256 + tid] = e;
      de += (double)e;
    }
#pragma unroll
    for (int sh = 1; sh < 64; sh <<= 1) de += __shfl_xor(de, sh);
    if ((tid & 63) == 0) lacc[tid >> 6] = de;
    __syncthreads();
    if (tid == 0) wpart[bid] = (lacc[0] + lacc[1]) + (lacc[2] + lacc[3]);
  } else if (bid < 768) {
    // ---- cosine path (r < P), f64, + fused stable top-10 selection ----
    const int b = bid - 512;
    if (tid < 32)
      reinterpret_cast<float4*>(sbuf)[tid] =
          reinterpret_cast<const float4*>(v2 + (size_t)b * D_)[tid];
    else if (tid < 64)
      reinterpret_cast<float4*>(sbuf)[tid] =
          reinterpret_cast<const float4*>(v1 + (size_t)b * D_)[tid - 32];
    __syncthreads();
    if (tid < 64) {
      const float2* s2 = reinterpret_cast<const float2*>(sbuf);
      const float2 a = s2[tid];
      const float2 c = s2[64 + tid];
      double dn2 = (double)a.x * a.x + (double)a.y * a.y;
      double dn1 = (double)c.x * c.x + (double)c.y * c.y;
#pragma unroll
      for (int sh = 1; sh < 64; sh <<= 1) {
        dn2 += __shfl_xor(dn2, sh);
        dn1 += __shfl_xor(dn1, sh);
      }
      if (tid == 0) { dinv[0] = 1.0 / sqrt(dn1); dinv[1] = 1.0 / sqrt(dn2); }
    }
    if (tid >= 128 && tid < 128 + P_) {
      const int r = tid - 128;
      const int row = idx[(size_t)b * KP_ + r];
      const float4* __restrict__ w2p = reinterpret_cast<const float4*>(mem2 + (size_t)row * D_);
      const float4* __restrict__ x2p = reinterpret_cast<const float4*>(sbuf);
      double sn2 = 0, ss = 0;
#pragma unroll 4
      for (int jj = 0; jj < 32; ++jj) {
        const float4 cc = w2p[jj];
        const float4 y2 = x2p[jj];
        sn2 += (double)cc.x * cc.x + (double)cc.y * cc.y + (double)cc.z * cc.z + (double)cc.w * cc.w;
        ss  += (double)cc.x * y2.x + (double)cc.y * y2.y + (double)cc.z * y2.z + (double)cc.w * y2.w;
      }
      dsn2[r] = sn2; dss[r] = ss;
    }
    double so = 0, sn1 = 0, st = 0;
    if (tid < P_) {
      const int row = idx[(size_t)b * KP_ + tid];
      const float4* __restrict__ w1p = reinterpret_cast<const float4*>(mem1 + (size_t)row * D_);
      const float4* __restrict__ x2p = reinterpret_cast<const float4*>(sbuf);
      const float4* __restrict__ x1p = reinterpret_cast<const float4*>(sbuf + D_);
#pragma unroll 4
      for (int jj = 0; jj < 32; ++jj) {
        const float4 a  = w1p[jj];
        const float4 y1 = x1p[jj];
        const float4 y2 = x2p[jj];
        so  += (double)a.x * y2.x + (double)a.y * y2.y + (double)a.z * y2.z + (double)a.w * y2.w;
        sn1 += (double)a.x * a.x  + (double)a.y * a.y  + (double)a.z * a.z  + (double)a.w * a.w;
        st  += (double)a.x * y1.x + (double)a.y * y1.y + (double)a.z * y1.z + (double)a.w * y1.w;
      }
    }
    __syncthreads();
    if (tid < P_) {
      const double t_rel = st * dinv[0] / sqrt(sn1);
      const double s_rel = dss[tid] * dinv[1] / sqrt(dsn2[tid]);
      sdiff[tid] = t_rel - s_rel;
      swout[tid] = expf((float)(so * (1.0 / (double)T_)));
    }
    __syncthreads();
    if (tid < 64) {
      const int l = tid;
      const double va = sdiff[l];
      const double vb = (l < P_ - 64) ? sdiff[l + 64] : -1.0e300;
      bool ta = false, tb = (l >= P_ - 64);
      int sel[P2_];
#pragma unroll
      for (int t = 0; t < P2_; ++t) {
        double cv; int cj;
        const bool aok = !ta, bok = !tb;
        if (aok && (!bok || va >= vb)) { cv = va; cj = l; }
        else if (bok)                  { cv = vb; cj = l + 64; }
        else                           { cv = -1.0e300; cj = 0x7fffffff; }
#pragma unroll
        for (int sh = 1; sh < 64; sh <<= 1) {
          const double ov = __shfl_xor(cv, sh);
          const int    oj = __shfl_xor(cj, sh);
          if (ov > cv || (ov == cv && oj < cj)) { cv = ov; cj = oj; }
        }
        sel[t] = cj;
        if (cj == l) ta = true;
        if (cj == l + 64) tb = true;
      }
      if (l == 0) {
        sel[0] = 0;  // .at[:,0].set(0) applied AFTER taking top-P2
        double sp = 0.0;
#pragma unroll
        for (int t = 0; t < P2_; ++t) {
          const float e = swout[sel[t]];
          out[(size_t)b * OC_ + t] = e;  // unnormalized
          sp += (double)e;
        }
        wpart[512 + b] = sp;
      }
    }
  } else if (tid < 64) {
    // ---- y-row momentum update + normalize (after copy; separate launch) ----
    const int b = bid - 768;
    const int row = y[b];
    const float2 m = *reinterpret_cast<const float2*>(mem1 + (size_t)row * D_ + tid * 2);
    const float2 a = *reinterpret_cast<const float2*>(v1 + (size_t)b * D_ + tid * 2);
    float2 l;
    l.x = m.x * 0.5f + a.x * 0.5f;
    l.y = m.y * 0.5f + a.y * 0.5f;
    float n = l.x * l.x + l.y * l.y;
#pragma unroll
    for (int sh = 1; sh < 64; sh <<= 1) n += __shfl_xor(n, sh);
    const float inv = 1.0f / sqrtf(n);
    float2 o;
    o.x = l.x * inv;
    o.y = l.y * inv;
    *reinterpret_cast<float2*>(outmem + (size_t)row * D_ + tid * 2) = o;
  }
}

// ---------------- shared: reduce partials -> 1/Z ----------------
__global__ __launch_bounds__(256) void k_z(
    const double* __restrict__ wpart, const int n, float* __restrict__ invz)
{
  __shared__ double lds[4];
  const int tid = threadIdx.x;
  double s = 0.0;
  for (int i = tid; i < n; i += 256) s += wpart[i];
#pragma unroll
  for (int sh = 1; sh < 64; sh <<= 1) s += __shfl_xor(s, sh);
  if ((tid & 63) == 0) lds[tid >> 6] = s;
  __syncthreads();
  if (tid == 0) {
    const double S = (lds[0] + lds[1]) + (lds[2] + lds[3]);
    const double Z = S / ((double)B_ * (double)OC_) * (double)N_;
    *invz = (float)(1.0 / Z);
  }
}

// ---------------- shared: scale score region by 1/Z ----------------
__global__ __launch_bounds__(256) void k_scale(
    float* __restrict__ out, const float* __restrict__ invz)
{
  const size_t i = (size_t)blockIdx.x * blockDim.x + threadIdx.x;
  constexpr size_t n4 = (size_t)B_ * OC_ / 4;  // 262784, exact
  if (i < n4) {
    const float sc = *invz;
    float4 v = reinterpret_cast<float4*>(out)[i];
    v.x *= sc; v.y *= sc; v.z *= sc; v.w *= sc;
    reinterpret_cast<float4*>(out)[i] = v;
  }
}

// ============================ FALLBACK (R2, proven) =============================
constexpr int FNNEG_ = B_ * (K_ / 256);   // 4096
__global__ __launch_bounds__(256) void fb_gather(
    const float* __restrict__ v1, const float* __restrict__ v2,
    const int* __restrict__ idx, const float* __restrict__ mem1,
    const float* __restrict__ mem2, float* __restrict__ out,
    double* __restrict__ wdiff, float* __restrict__ woutp,
    double* __restrict__ wpart)
{
  const int tid = threadIdx.x;
  if (blockIdx.x < FNNEG_) {
    const int b = blockIdx.x >> 4;
    const int c = blockIdx.x & 15;
    const int wave = tid >> 6;
    const int lane = tid & 63;
    const int g = lane >> 3;
    const int j = lane & 7;
    const float4* __restrict__ v2p = reinterpret_cast<const float4*>(v2 + (size_t)b * D_);
    float4 x0 = v2p[j], x1 = v2p[j + 8], x2 = v2p[j + 16], x3 = v2p[j + 24];
    const int* __restrict__ idxb = idx + (size_t)b * KP_ + P_ + (c << 8) + (wave << 6) + g;
    float* __restrict__ outb = out + (size_t)b * OC_ + P2_ + (c << 8) + (wave << 6) + g;
    double de = 0.0;
#pragma unroll
    for (int t = 0; t < 8; t += 2) {
      const int row0 = idxb[t * 8];
      const int row1 = idxb[t * 8 + 8];
      const float4* __restrict__ p0 = reinterpret_cast<const float4*>(mem1 + (size_t)row0 * D_);
      const float4* __restrict__ p1 = reinterpret_cast<const float4*>(mem1 + (size_t)row1 * D_);
      const float4 a0 = p0[j], a1 = p0[j + 8], a2 = p0[j + 16], a3 = p0[j + 24];
      const float4 b0 = p1[j], b1 = p1[j + 8], b2 = p1[j + 16], b3 = p1[j + 24];
      float s0 = a0.x * x0.x + a0.y * x0.y + a0.z * x0.z + a0.w * x0.w
               + a1.x * x1.x + a1.y * x1.y + a1.z * x1.z + a1.w * x1.w
               + a2.x * x2.x + a2.y * x2.y + a2.z * x2.z + a2.w * x2.w
               + a3.x * x3.x + a3.y * x3.y + a3.z * x3.z + a3.w * x3.w;
      float s1 = b0.x * x0.x + b0.y * x0.y + b0.z * x0.z + b0.w * x0.w
               + b1.x * x1.x + b1.y * x1.y + b1.z * x1.z + b1.w * x1.w
               + b2.x * x2.x + b2.y * x2.y + b2.z * x2.z + b2.w * x2.w
               + b3.x * x3.x + b3.y * x3.y + b3.z * x3.z + b3.w * x3.w;
#pragma unroll
      for (int sh = 1; sh < 8; sh <<= 1) {
        s0 += __shfl_xor(s0, sh);
        s1 += __shfl_xor(s1, sh);
      }
      if (j == 0) {
        const float e0 = expf(s0 * (1.0f / T_));
        const float e1 = expf(s1 * (1.0f / T_));
        outb[t * 8] = e0;
        outb[t * 8 + 8] = e1;
        de += (double)e0 + (double)e1;
      }
    }
#pragma unroll
    for (int sh = 1; sh < 64; sh <<= 1) de += __shfl_xor(de, sh);
    __shared__ double lacc[4];
    if (lane == 0) lacc[wave] = de;
    __syncthreads();
    if (tid == 0) wpart[blockIdx.x] = (lacc[0] + lacc[1]) + (lacc[2] + lacc[3]);
  } else {
    __shared__ float sbuf[2 * D_];
    const int b = blockIdx.x - FNNEG_;
    if (tid < 32)
      reinterpret_cast<float4*>(sbuf)[tid] =
          reinterpret_cast<const float4*>(v2 + (size_t)b * D_)[tid];
    else if (tid < 64)
      reinterpret_cast<float4*>(sbuf)[tid] =
          reinterpret_cast<const float4*>(v1 + (size_t)b * D_)[tid - 32];
    __syncthreads();
    if (tid < P_) {
      double n2 = 0.0, n1 = 0.0;
#pragma unroll 8
      for (int jj = 0; jj < D_; ++jj) {
        n2 += (double)sbuf[jj] * sbuf[jj];
        n1 += (double)sbuf[D_ + jj] * sbuf[D_ + jj];
      }
      const double inv_n1 = 1.0 / sqrt(n1);
      const double inv_n2 = 1.0 / sqrt(n2);
      const int row = idx[(size_t)b * KP_ + tid];
      const float4* __restrict__ w1p = reinterpret_cast<const float4*>(mem1 + (size_t)row * D_);
      const float4* __restrict__ w2p = reinterpret_cast<const float4*>(mem2 + (size_t)row * D_);
      const float4* __restrict__ x2p = reinterpret_cast<const float4*>(sbuf);
      const float4* __restrict__ x1p = reinterpret_cast<const float4*>(sbuf + D_);
      double so = 0, sn1 = 0, st = 0, sn2 = 0, ss = 0;
#pragma unroll 4
      for (int jj = 0; jj < 32; ++jj) {
        const float4 a  = w1p[jj];
        const float4 cc = w2p[jj];
        const float4 y1 = x1p[jj];
        const float4 y2 = x2p[jj];
        so  += (double)a.x * y2.x + (double)a.y * y2.y + (double)a.z * y2.z + (double)a.w * y2.w;
        sn1 += (double)a.x * a.x  + (double)a.y * a.y  + (double)a.z * a.z  + (double)a.w * a.w;
        st  += (double)a.x * y1.x + (double)a.y * y1.y + (double)a.z * y1.z + (double)a.w * y1.w;
        sn2 += (double)cc.x * cc.x + (double)cc.y * cc.y + (double)cc.z * cc.z + (double)cc.w * cc.w;
        ss  += (double)cc.x * y2.x + (double)cc.y * y2.y + (double)cc.z * y2.z + (double)cc.w * y2.w;
      }
      const double t_rel = st * inv_n1 / sqrt(sn1);
      const double s_rel = ss * inv_n2 / sqrt(sn2);
      wdiff[b * P_ + tid] = t_rel - s_rel;
      woutp[b * P_ + tid] = expf((float)(so * (1.0 / (double)T_)));
    }
  }
}

__global__ __launch_bounds__(64) void fb_select(
    const double* __restrict__ wdiff, const float* __restrict__ woutp,
    float* __restrict__ out, double* __restrict__ wpart)
{
  const int b = blockIdx.x;
  const int l = threadIdx.x;
  const double* __restrict__ db = wdiff + b * P_;
  const double va = db[l];
  const double vb = (l < P_ - 64) ? db[l + 64] : -1.0e300;
  bool ta = false, tb = (l >= P_ - 64);
  int sel[P2_];
#pragma unroll
  for (int t = 0; t < P2_; ++t) {
    double cv; int cj;
    const bool aok = !ta, bok = !tb;
    if (aok && (!bok || va >= vb)) { cv = va; cj = l; }
    else if (bok)                  { cv = vb; cj = l + 64; }
    else                           { cv = -1.0e300; cj = 0x7fffffff; }
#pragma unroll
    for (int sh = 1; sh < 64; sh <<= 1) {
      const double ov = __shfl_xor(cv, sh);
      const int    oj = __shfl_xor(cj, sh);
      if (ov > cv || (ov == cv && oj < cj)) { cv = ov; cj = oj; }
    }
    sel[t] = cj;
    if (cj == l) ta = true;
    if (cj == l + 64) tb = true;
  }
  if (l == 0) {
    sel[0] = 0;
    double sp = 0.0;
#pragma unroll
    for (int t = 0; t < P2_; ++t) {
      const float e = woutp[b * P_ + sel[t]];
      out[(size_t)b * OC_ + t] = e;
      sp += (double)e;
    }
    wpart[FNNEG_ + b] = sp;
  }
}

__global__ __launch_bounds__(256) void fb_copy(
    const float* __restrict__ src, float* __restrict__ dst)
{
  const size_t i = ((size_t)blockIdx.x * blockDim.x + threadIdx.x) * 4;
  const float4 v = *reinterpret_cast<const float4*>(src + i);
  *reinterpret_cast<float4*>(dst + i) = v;
}

__global__ __launch_bounds__(64) void fb_update(
    const float* __restrict__ mem1, const float* __restrict__ v1,
    const int* __restrict__ y, float* __restrict__ dst)
{
  const int b = blockIdx.x;
  const int lane = threadIdx.x;
  const int row = y[b];
  const float2 m = *reinterpret_cast<const float2*>(mem1 + (size_t)row * D_ + lane * 2);
  const float2 a = *reinterpret_cast<const float2*>(v1 + (size_t)b * D_ + lane * 2);
  float2 l;
  l.x = m.x * 0.5f + a.x * 0.5f;
  l.y = m.y * 0.5f + a.y * 0.5f;
  float n = l.x * l.x + l.y * l.y;
#pragma unroll
  for (int sh = 1; sh < 64; sh <<= 1) n += __shfl_xor(n, sh);
  const float inv = 1.0f / sqrtf(n);
  float2 o;
  o.x = l.x * inv;
  o.y = l.y * inv;
  *reinterpret_cast<float2*>(dst + (size_t)row * D_ + lane * 2) = o;
}

extern "C" void kernel_launch(void* const* d_in, const int* in_sizes, int n_in,
                              void* d_out, int out_size, void* d_ws, size_t ws_size,
                              hipStream_t stream) {
  // setup_inputs order: epoch, v1, v2, y, idx, memory_v1, memory_v2
  const float* v1   = (const float*)d_in[1];
  const float* v2   = (const float*)d_in[2];
  const int*   y    = (const int*)d_in[3];
  const int*   idx  = (const int*)d_in[4];
  const float* mem1 = (const float*)d_in[5];
  const float* mem2 = (const float*)d_in[6];

  float* out    = (float*)d_out;                      // (B, P2+K) scores
  float* outmem = out + (size_t)B_ * OC_;             // (N, D) new memory

  char* ws = (char*)d_ws;
  constexpr size_t SSZ = (size_t)B_ * N_ * 4;         // 67,108,864 B
  constexpr size_t NEED = SSZ + 8192 + 2 * 65536 + 4096;

  if (ws_size >= NEED) {
    float*          S     = (float*)ws;
    double*         wpart = (double*)(ws + SSZ);                  // 768 doubles
    unsigned short* v2h   = (unsigned short*)(ws + SSZ + 8192);
    unsigned short* v2l   = (unsigned short*)(ws + SSZ + 8192 + 65536);
    float*          invz  = (float*)(ws + SSZ + 8192 + 2 * 65536);

    k_prep<<<32, 256, 0, stream>>>(v2, v2h, v2l);
    k_gemm<<<GEMMB_ + 2048, 512, 0, stream>>>(mem1, v2h, v2l, S, outmem);
    k_score<<<1024, 256, 0, stream>>>(v1, v2, idx, mem1, mem2, S, y,
                                      out, outmem, wpart);
    k_z<<<1, 256, 0, stream>>>(wpart, 768, invz);
    k_scale<<<(B_ * OC_ / 4 + 255) / 256, 256, 0, stream>>>(out, invz);
  } else {
    double* wpart = (double*)ws;                                   // 4352 doubles
    double* wdiff = (double*)(ws + 65536);                         // B*P doubles
    float*  woutp = (float*)(ws + 65536 + 204800);
    float*  invz  = (float*)(ws + 65536 + 204800 + 102400);
    fb_gather<<<FNNEG_ + B_, 256, 0, stream>>>(v1, v2, idx, mem1, mem2,
                                               out, wdiff, woutp, wpart);
    fb_select<<<B_, 64, 0, stream>>>(wdiff, woutp, out, wpart);
    k_z<<<1, 256, 0, stream>>>(wpart, FNNEG_ + B_, invz);
    k_scale<<<(B_ * OC_ / 4 + 255) / 256, 256, 0, stream>>>(out, invz);
    fb_copy<<<(N_ * D_) / (256 * 4), 256, 0, stream>>>(mem1, outmem);
    fb_update<<<B_, 64, 0, stream>>>(mem1, v1, y, outmem);
  }
}

// Round 8
// 77.469 us; speedup vs baseline: 1.0510x; 1.0510x over previous
//
#include <hip/hip_runtime.h>
#include <math.h>

constexpr int B_ = 256;
constexpr int D_ = 128;
constexpr int N_ = 65536;
constexpr int P_ = 100;
constexpr int K_ = 4096;
constexpr int P2_ = 10;
constexpr int KP_ = K_ + P_;       // 4196
constexpr int OC_ = P2_ + K_;      // 4106
constexpr int NT_ = 512;           // row-tiles (row>>7)
constexpr int SLOT_ = 2560;        // per-tile list capacity (mean 2048, sd 45)
constexpr float T_ = 0.07f;

typedef __attribute__((ext_vector_type(8))) short bf16x8;
typedef __attribute__((ext_vector_type(4))) float f32x4v;

// ---- kernel P: split v2 into bf16 hi/lo; block 32 zeroes gcount ----
__global__ __launch_bounds__(256) void k_prep(
    const float* __restrict__ v2, unsigned short* __restrict__ v2h,
    unsigned short* __restrict__ v2l, int* __restrict__ gcount)
{
  const int tid = threadIdx.x;
  if (blockIdx.x == 32) {                          // zero the 512 tile counters
    gcount[tid] = 0;
    gcount[tid + 256] = 0;
    return;
  }
  const int i4 = blockIdx.x * 256 + tid;           // 8192 float4 total
  const float4 v = reinterpret_cast<const float4*>(v2)[i4];
  const float f[4] = {v.x, v.y, v.z, v.w};
  unsigned short h[4], l[4];
#pragma unroll
  for (int j = 0; j < 4; ++j) {
    const unsigned u = __float_as_uint(f[j]);
    h[j] = (unsigned short)(u >> 16);
    const float al = f[j] - __uint_as_float(u & 0xFFFF0000u);
    l[j] = (unsigned short)(__float_as_uint(al) >> 16);
  }
  ushort4 hv = {h[0], h[1], h[2], h[3]};
  ushort4 lv = {l[0], l[1], l[2], l[3]};
  reinterpret_cast<ushort4*>(v2h)[i4] = hv;
  reinterpret_cast<ushort4*>(v2l)[i4] = lv;
}

// ---- kernel B: bin (b,k) entries by row-tile ----
// entry u32 = (rowlocal 7b << 20) | (b 8b << 12) | (k 12b)
__global__ __launch_bounds__(256) void k_bin(
    const int* __restrict__ idx, unsigned* __restrict__ lists,
    int* __restrict__ gcount)
{
  const int b = blockIdx.x;
  const int tid = threadIdx.x;
  __shared__ int cnt[NT_];
  __shared__ int gbase[NT_];
  cnt[tid] = 0; cnt[tid + 256] = 0;
  __syncthreads();
  const int4* __restrict__ src = reinterpret_cast<const int4*>(idx + (size_t)b * KP_ + P_);
  unsigned short rows[16];
#pragma unroll
  for (int q = 0; q < 4; ++q) {
    const int4 r = src[q * 256 + tid];
    rows[q * 4 + 0] = (unsigned short)r.x;
    rows[q * 4 + 1] = (unsigned short)r.y;
    rows[q * 4 + 2] = (unsigned short)r.z;
    rows[q * 4 + 3] = (unsigned short)r.w;
    atomicAdd(&cnt[r.x >> 7], 1);
    atomicAdd(&cnt[r.y >> 7], 1);
    atomicAdd(&cnt[r.z >> 7], 1);
    atomicAdd(&cnt[r.w >> 7], 1);
  }
  __syncthreads();
  for (int t = tid; t < NT_; t += 256) {
    const int c = cnt[t];
    gbase[t] = c ? atomicAdd(&gcount[t], c) : 0;
  }
  __syncthreads();
  for (int t = tid; t < NT_; t += 256) cnt[t] = 0;   // reuse as cursor
  __syncthreads();
#pragma unroll
  for (int q = 0; q < 4; ++q) {
#pragma unroll
    for (int u = 0; u < 4; ++u) {
      const int row = rows[q * 4 + u];
      const int tile = row >> 7;
      const int off = atomicAdd(&cnt[tile], 1);
      const int pos = gbase[tile] + off;
      if (pos < SLOT_)
        lists[(size_t)tile * SLOT_ + pos] =
            ((unsigned)(row & 127) << 20) | ((unsigned)b << 12) |
            (unsigned)((q * 256 + tid) * 4 + u);
    }
  }
}

__device__ inline void split8(const f32x4v lo, const f32x4v hi,
                              bf16x8& h, bf16x8& l) {
#pragma unroll
  for (int j = 0; j < 4; ++j) {
    const unsigned u = __float_as_uint(lo[j]);
    h[j] = (short)(u >> 16);
    const float al = lo[j] - __uint_as_float(u & 0xFFFF0000u);
    l[j] = (short)(__float_as_uint(al) >> 16);
  }
#pragma unroll
  for (int j = 0; j < 4; ++j) {
    const unsigned u = __float_as_uint(hi[j]);
    h[4 + j] = (short)(u >> 16);
    const float al = hi[j] - __uint_as_float(u & 0xFFFF0000u);
    l[4 + j] = (short)(__float_as_uint(al) >> 16);
  }
}

// ---- kernel M: [0,512) GEMM+fused exp/scatter; [512,768) cos+select;
//                [768,2816) copy memory_v1 -> outmem ----
__global__ __launch_bounds__(512) void k_mega(
    const float* __restrict__ v1, const float* __restrict__ v2,
    const int* __restrict__ idx, const float* __restrict__ mem1,
    const float* __restrict__ mem2, const unsigned short* __restrict__ v2h,
    const unsigned short* __restrict__ v2l, const unsigned* __restrict__ lists,
    const int* __restrict__ gcount, float* __restrict__ out,
    float* __restrict__ outmem, double* __restrict__ wpart)
{
  const int tid = threadIdx.x;
  const unsigned bid = blockIdx.x;
  __shared__ char smem[66048];        // staging 64KB | epilogue [128][129] f32
  __shared__ double lacc8[8];
  __shared__ float sbuf[2 * D_];
  __shared__ double sdiff[P_];
  __shared__ float swout[P_];
  __shared__ double dsn2[P_], dss[P_];
  __shared__ double dinv[2];

  if (bid < 512) {
    // ================= GEMM tile + fused epilogue =================
    const int r0 = bid * 128;
    {
      const float4* __restrict__ gsrc = reinterpret_cast<const float4*>(mem1 + (size_t)r0 * D_);
#pragma unroll
      for (int q = 0; q < 8; ++q) {
        const int li = q * 512 + tid;              // float4 index
        const float4 v = gsrc[li];
        const int row = li >> 5;
        const int off = (li & 31) * 16;
        *reinterpret_cast<float4*>(smem + row * 512 + (off ^ ((row & 7) << 4))) = v;
      }
    }
    __syncthreads();
    const int wid = tid >> 6, lane = tid & 63;
    const int mb = (wid >> 1) * 64;                // b-offset of wave tile
    const int nb = (wid & 1) * 64;                 // row-offset of wave tile
    const int klane8 = (lane >> 4) * 8;
    f32x4v acc[4][4];
#pragma unroll
    for (int m = 0; m < 4; ++m)
#pragma unroll
      for (int n = 0; n < 4; ++n) acc[m][n] = {0.f, 0.f, 0.f, 0.f};

    const char* tb = (const char*)smem;
#pragma unroll
    for (int kk = 0; kk < 4; ++kk) {
      const int ks = kk * 32;
      bf16x8 ah[4], al[4];
#pragma unroll
      for (int m = 0; m < 4; ++m) {
        const size_t o = (size_t)(mb + m * 16 + (lane & 15)) * D_ + ks + klane8;
        ah[m] = *reinterpret_cast<const bf16x8*>(v2h + o);
        al[m] = *reinterpret_cast<const bf16x8*>(v2l + o);
      }
#pragma unroll
      for (int n = 0; n < 4; ++n) {
        const int r_loc = nb + n * 16 + (lane & 15);
        const int sw = (r_loc & 7) << 4;
        const int kb = (ks + klane8) * 4;
        const char* rb = tb + r_loc * 512;
        const f32x4v p0 = *reinterpret_cast<const f32x4v*>(rb + ((kb) ^ sw));
        const f32x4v p1 = *reinterpret_cast<const f32x4v*>(rb + ((kb + 16) ^ sw));
        bf16x8 bh, bl;
        split8(p0, p1, bh, bl);
#pragma unroll
        for (int m = 0; m < 4; ++m) {
          acc[m][n] = __builtin_amdgcn_mfma_f32_16x16x32_bf16(ah[m], bh, acc[m][n], 0, 0, 0);
          acc[m][n] = __builtin_amdgcn_mfma_f32_16x16x32_bf16(ah[m], bl, acc[m][n], 0, 0, 0);
          acc[m][n] = __builtin_amdgcn_mfma_f32_16x16x32_bf16(al[m], bh, acc[m][n], 0, 0, 0);
        }
      }
    }
    // -------- epilogue: LDS tile (two b-halves) -> exp -> scatter --------
    __syncthreads();                                // all MFMA reads done
    float* eL = (float*)smem;                       // [128 rows][129] f32
    const int tile = bid;
    const int cntT = min(gcount[tile], SLOT_);
    const unsigned* __restrict__ lb = lists + (size_t)tile * SLOT_;
    double de = 0.0;
#pragma unroll
    for (int half = 0; half < 2; ++half) {
      if ((mb < 128) == (half == 0)) {
#pragma unroll
        for (int m = 0; m < 4; ++m)
#pragma unroll
          for (int n = 0; n < 4; ++n) {
            const int rowloc = nb + n * 16 + (lane & 15);
            const int bloc = (mb & 64) + m * 16 + (lane >> 4) * 4;
#pragma unroll
            for (int reg = 0; reg < 4; ++reg)
              eL[rowloc * 129 + bloc + reg] = acc[m][n][reg];
          }
      }
      __syncthreads();
      for (int i = tid; i < cntT; i += 512) {
        const unsigned e = lb[i];
        const int bb = (e >> 12) & 255;
        if ((bb >> 7) == half) {
          const int rl = e >> 20;
          const int k = e & 4095;
          const float ex = expf(eL[rl * 129 + (bb & 127)] * (1.0f / T_));
          out[(size_t)bb * OC_ + P2_ + k] = ex;     // unnormalized
          de += (double)ex;
        }
      }
      __syncthreads();
    }
#pragma unroll
    for (int sh = 1; sh < 64; sh <<= 1) de += __shfl_xor(de, sh);
    if ((tid & 63) == 0) lacc8[tid >> 6] = de;
    __syncthreads();
    if (tid == 0) {
      double s = 0.0;
#pragma unroll
      for (int w = 0; w < 8; ++w) s += lacc8[w];
      wpart[bid] = s;
    }
  } else if (bid < 768) {
    // ================= cosine path (r < P) + stable top-10 =================
    const int b = bid - 512;
    if (tid < 32)
      reinterpret_cast<float4*>(sbuf)[tid] =
          reinterpret_cast<const float4*>(v2 + (size_t)b * D_)[tid];
    else if (tid < 64)
      reinterpret_cast<float4*>(sbuf)[tid] =
          reinterpret_cast<const float4*>(v1 + (size_t)b * D_)[tid - 32];
    __syncthreads();
    if (tid < 64) {
      const float2* s2 = reinterpret_cast<const float2*>(sbuf);
      const float2 a = s2[tid];
      const float2 c = s2[64 + tid];
      double dn2 = (double)a.x * a.x + (double)a.y * a.y;
      double dn1 = (double)c.x * c.x + (double)c.y * c.y;
#pragma unroll
      for (int sh = 1; sh < 64; sh <<= 1) {
        dn2 += __shfl_xor(dn2, sh);
        dn1 += __shfl_xor(dn1, sh);
      }
      if (tid == 0) { dinv[0] = 1.0 / sqrt(dn1); dinv[1] = 1.0 / sqrt(dn2); }
    }
    if (tid >= 128 && tid < 128 + P_) {
      const int r = tid - 128;
      const int row = idx[(size_t)b * KP_ + r];
      const float4* __restrict__ w2p = reinterpret_cast<const float4*>(mem2 + (size_t)row * D_);
      const float4* __restrict__ x2p = reinterpret_cast<const float4*>(sbuf);
      double sn2 = 0, ss = 0;
#pragma unroll 4
      for (int jj = 0; jj < 32; ++jj) {
        const float4 cc = w2p[jj];
        const float4 y2 = x2p[jj];
        sn2 += (double)cc.x * cc.x + (double)cc.y * cc.y + (double)cc.z * cc.z + (double)cc.w * cc.w;
        ss  += (double)cc.x * y2.x + (double)cc.y * y2.y + (double)cc.z * y2.z + (double)cc.w * y2.w;
      }
      dsn2[r] = sn2; dss[r] = ss;
    }
    double so = 0, sn1 = 0, st = 0;
    if (tid < P_) {
      const int row = idx[(size_t)b * KP_ + tid];
      const float4* __restrict__ w1p = reinterpret_cast<const float4*>(mem1 + (size_t)row * D_);
      const float4* __restrict__ x2p = reinterpret_cast<const float4*>(sbuf);
      const float4* __restrict__ x1p = reinterpret_cast<const float4*>(sbuf + D_);
#pragma unroll 4
      for (int jj = 0; jj < 32; ++jj) {
        const float4 a  = w1p[jj];
        const float4 y1 = x1p[jj];
        const float4 y2 = x2p[jj];
        so  += (double)a.x * y2.x + (double)a.y * y2.y + (double)a.z * y2.z + (double)a.w * y2.w;
        sn1 += (double)a.x * a.x  + (double)a.y * a.y  + (double)a.z * a.z  + (double)a.w * a.w;
        st  += (double)a.x * y1.x + (double)a.y * y1.y + (double)a.z * y1.z + (double)a.w * y1.w;
      }
    }
    __syncthreads();
    if (tid < P_) {
      const double t_rel = st * dinv[0] / sqrt(sn1);
      const double s_rel = dss[tid] * dinv[1] / sqrt(dsn2[tid]);
      sdiff[tid] = t_rel - s_rel;
      swout[tid] = expf((float)(so * (1.0 / (double)T_)));
    }
    __syncthreads();
    if (tid < 64) {
      const int l = tid;
      const double va = sdiff[l];
      const double vb = (l < P_ - 64) ? sdiff[l + 64] : -1.0e300;
      bool ta = false, tb2 = (l >= P_ - 64);
      int sel[P2_];
#pragma unroll
      for (int t = 0; t < P2_; ++t) {
        double cv; int cj;
        const bool aok = !ta, bok = !tb2;
        if (aok && (!bok || va >= vb)) { cv = va; cj = l; }
        else if (bok)                  { cv = vb; cj = l + 64; }
        else                           { cv = -1.0e300; cj = 0x7fffffff; }
#pragma unroll
        for (int sh = 1; sh < 64; sh <<= 1) {
          const double ov = __shfl_xor(cv, sh);
          const int    oj = __shfl_xor(cj, sh);
          if (ov > cv || (ov == cv && oj < cj)) { cv = ov; cj = oj; }
        }
        sel[t] = cj;
        if (cj == l) ta = true;
        if (cj == l + 64) tb2 = true;
      }
      if (l == 0) {
        sel[0] = 0;  // .at[:,0].set(0) applied AFTER taking top-P2
        double sp = 0.0;
#pragma unroll
        for (int t = 0; t < P2_; ++t) {
          const float e = swout[sel[t]];
          out[(size_t)b * OC_ + t] = e;  // unnormalized
          sp += (double)e;
        }
        wpart[512 + b] = sp;
      }
    }
  } else {
    // ================= copy memory_v1 -> outmem =================
    const int g = bid - 768;                        // 2048 blocks x 1024 float4
    const float4* __restrict__ s4 = reinterpret_cast<const float4*>(mem1) + (size_t)g * 1024;
    float4* __restrict__ d4 = reinterpret_cast<float4*>(outmem) + (size_t)g * 1024;
    d4[tid] = s4[tid];
    d4[tid + 512] = s4[tid + 512];
  }
}

// ---------------- kernel Z: reduce partials -> 1/Z ----------------
__global__ __launch_bounds__(256) void k_z(
    const double* __restrict__ wpart, float* __restrict__ invz)
{
  __shared__ double lds[4];
  const int tid = threadIdx.x;
  double s = 0.0;
  for (int i = tid; i < 768; i += 256) s += wpart[i];
#pragma unroll
  for (int sh = 1; sh < 64; sh <<= 1) s += __shfl_xor(s, sh);
  if ((tid & 63) == 0) lds[tid >> 6] = s;
  __syncthreads();
  if (tid == 0) {
    const double S = (lds[0] + lds[1]) + (lds[2] + lds[3]);
    const double Z = S / ((double)B_ * (double)OC_) * (double)N_;
    *invz = (float)(1.0 / Z);
  }
}

// ---------------- kernel S: scale scores by 1/Z + y-row update ----------
constexpr int NSC_ = (B_ * OC_ / 4 + 255) / 256;  // 1027 scale blocks
__global__ __launch_bounds__(256) void k_scale_upd(
    float* __restrict__ out, const float* __restrict__ invz,
    const float* __restrict__ mem1, const float* __restrict__ v1,
    const int* __restrict__ y, float* __restrict__ dst)
{
  const int tid = threadIdx.x;
  if (blockIdx.x < NSC_) {
    const size_t i = (size_t)blockIdx.x * 256 + tid;
    constexpr size_t n4 = (size_t)B_ * OC_ / 4;
    if (i < n4) {
      const float sc = *invz;
      float4 v = reinterpret_cast<float4*>(out)[i];
      v.x *= sc; v.y *= sc; v.z *= sc; v.w *= sc;
      reinterpret_cast<float4*>(out)[i] = v;
    }
  } else if (tid < 64) {
    const int b = blockIdx.x - NSC_;
    const int row = y[b];
    const float2 m = *reinterpret_cast<const float2*>(mem1 + (size_t)row * D_ + tid * 2);
    const float2 a = *reinterpret_cast<const float2*>(v1 + (size_t)b * D_ + tid * 2);
    float2 l;
    l.x = m.x * 0.5f + a.x * 0.5f;
    l.y = m.y * 0.5f + a.y * 0.5f;
    float n = l.x * l.x + l.y * l.y;
#pragma unroll
    for (int sh = 1; sh < 64; sh <<= 1) n += __shfl_xor(n, sh);
    const float inv = 1.0f / sqrtf(n);
    float2 o;
    o.x = l.x * inv;
    o.y = l.y * inv;
    *reinterpret_cast<float2*>(dst + (size_t)row * D_ + tid * 2) = o;
  }
}

extern "C" void kernel_launch(void* const* d_in, const int* in_sizes, int n_in,
                              void* d_out, int out_size, void* d_ws, size_t ws_size,
                              hipStream_t stream) {
  // setup_inputs order: epoch, v1, v2, y, idx, memory_v1, memory_v2
  const float* v1   = (const float*)d_in[1];
  const float* v2   = (const float*)d_in[2];
  const int*   y    = (const int*)d_in[3];
  const int*   idx  = (const int*)d_in[4];
  const float* mem1 = (const float*)d_in[5];
  const float* mem2 = (const float*)d_in[6];

  float* out    = (float*)d_out;                      // (B, P2+K) scores
  float* outmem = out + (size_t)B_ * OC_;             // (N, D) new memory

  char* ws = (char*)d_ws;
  constexpr size_t LSZ = (size_t)NT_ * SLOT_ * 4;     // 5,242,880 B
  unsigned*       lists  = (unsigned*)ws;
  int*            gcount = (int*)(ws + LSZ);                    // 512 ints
  unsigned short* v2h    = (unsigned short*)(ws + LSZ + 4096);
  unsigned short* v2l    = (unsigned short*)(ws + LSZ + 4096 + 65536);
  double*         wpart  = (double*)(ws + LSZ + 4096 + 2 * 65536);  // 768 doubles
  float*          invz   = (float*)(ws + LSZ + 4096 + 2 * 65536 + 8192);

  k_prep<<<33, 256, 0, stream>>>(v2, v2h, v2l, gcount);
  k_bin<<<B_, 256, 0, stream>>>(idx, lists, gcount);
  k_mega<<<2816, 512, 0, stream>>>(v1, v2, idx, mem1, mem2, v2h, v2l,
                                   lists, gcount, out, outmem, wpart);
  k_z<<<1, 256, 0, stream>>>(wpart, invz);
  k_scale_upd<<<NSC_ + B_, 256, 0, stream>>>(out, invz, mem1, v1, y, outmem);
}